// Round 5
// baseline (5960.681 us; speedup 1.0000x reference)
//
#include <hip/hip_runtime.h>
#include <hip/hip_bf16.h>
#include <math.h>

#define BQ   512
#define EDIM 512
#define HDIM 1024
#define VDIM 1024
#define TLEN 32
#define TOUT 33
#define PLS  (BQ * VDIM)       // logits partial plane stride

typedef _Float16 half8  __attribute__((ext_vector_type(8)));
typedef _Float16 half4v __attribute__((ext_vector_type(4)));
typedef float    f32x16 __attribute__((ext_vector_type(16)));

#define GLOAD_LDS16(gp, lp) __builtin_amdgcn_global_load_lds( \
    (const __attribute__((address_space(1))) void*)(gp),      \
    (__attribute__((address_space(3))) void*)(lp), 16, 0, 0)

// ---------------------------------------------------------------------------
// Static device buffers — every buffer write-before-read per call.
// f16 split planes: value = hi + lo/4096 (lo pre-scaled by 2^12)
// ---------------------------------------------------------------------------
__device__ _Float16 g_curh[BQ*EDIM], g_curl[BQ*EDIM];
__device__ _Float16 g_h0h[BQ*HDIM], g_h0l[BQ*HDIM];
__device__ _Float16 g_h1h[BQ*HDIM], g_h1l[BQ*HDIM];
__device__ _Float16 g_hnh[BQ*HDIM], g_hnl[BQ*HDIM];
__device__ float    g_c0[BQ*HDIM], g_c1[BQ*HDIM];

__device__ _Float16 g_wih0h[4*HDIM*EDIM], g_wih0l[4*HDIM*EDIM];
__device__ _Float16 g_whh0h[4*HDIM*HDIM], g_whh0l[4*HDIM*HDIM];
__device__ _Float16 g_wih1h[4*HDIM*HDIM], g_wih1l[4*HDIM*HDIM];
__device__ _Float16 g_whh1h[4*HDIM*HDIM], g_whh1l[4*HDIM*HDIM];
__device__ _Float16 g_wouth[VDIM*HDIM],   g_woutl[VDIM*HDIM];

__device__ float g_gates[BQ * 4 * HDIM];   // gate pre-activations (bias included)
__device__ float g_part_lg[4 * PLS];       // logits split-K partials (S=4)
__device__ float g_bsum0[4*HDIM], g_bsum1[4*HDIM];

// ---------------------------------------------------------------------------
__global__ void init_kernel(float* __restrict__ out,
                            const float* __restrict__ bi0, const float* __restrict__ bh0,
                            const float* __restrict__ bi1, const float* __restrict__ bh1) {
    int i = blockIdx.x * 256 + threadIdx.x;   // [0, BQ*HDIM)
    g_c0[i] = 0.f; g_c1[i] = 0.f;
    g_h0h[i] = (_Float16)0.f; g_h0l[i] = (_Float16)0.f;
    g_h1h[i] = (_Float16)0.f; g_h1l[i] = (_Float16)0.f;
    if (i < 4 * HDIM) {
        g_bsum0[i] = bi0[i] + bh0[i];
        g_bsum1[i] = bi1[i] + bh1[i];
    }
    if (i < 3 * BQ) {
        int which = i / BQ, b = i % BQ;
        out[(size_t)which * BQ * TOUT + (size_t)b * TOUT + (TOUT - 1)] = 0.f;
    }
}

// ---------------------------------------------------------------------------
// fp32 -> (hi, lo*2^12) f16 split
// ---------------------------------------------------------------------------
__global__ void split_kernel(const float* __restrict__ w, _Float16* __restrict__ hi,
                             _Float16* __restrict__ lo, int nquads) {
    int q = blockIdx.x * 256 + threadIdx.x;
    if (q >= nquads) return;
    float4 v = ((const float4*)w)[q];
    half4v h, l;
    h[0] = (_Float16)v.x; l[0] = (_Float16)((v.x - (float)h[0]) * 4096.f);
    h[1] = (_Float16)v.y; l[1] = (_Float16)((v.y - (float)h[1]) * 4096.f);
    h[2] = (_Float16)v.z; l[2] = (_Float16)((v.z - (float)h[2]) * 4096.f);
    h[3] = (_Float16)v.w; l[3] = (_Float16)((v.w - (float)h[3]) * 4096.f);
    ((half4v*)hi)[q] = h;
    ((half4v*)lo)[q] = l;
}

__device__ __forceinline__ void split1(float x, _Float16* hp, _Float16* lp) {
    _Float16 h = (_Float16)x;
    *hp = h;
    *lp = (_Float16)((x - (float)h) * 4096.f);
}

// ---------------------------------------------------------------------------
// MFMA GEMM, tile 64(M)x128(N), 4 waves (wave w owns n-strip w*32), BK=32.
// Fragment-linear LDS (conflict-free reads at lane*16B), double-buffered,
// one barrier per K-iter. A = Ah + Al/4096, W = Wh + Wl/4096.
// Split-K over blockIdx.z (S planes); bias added when bias != nullptr.
//   out(+ s*BQ*N)[m][n] = sum_k A[m][k] W[n][k] (+ bias[n])
// ---------------------------------------------------------------------------
__global__ __launch_bounds__(256) void gemm_f16split(
    const _Float16* __restrict__ Ah1, const _Float16* __restrict__ Al1, int K1,
    const _Float16* __restrict__ Wh1, const _Float16* __restrict__ Wl1,
    const _Float16* __restrict__ Ah2, const _Float16* __restrict__ Al2, int K2,
    const _Float16* __restrict__ Wh2, const _Float16* __restrict__ Wl2,
    const float* __restrict__ bias, float* __restrict__ outp, int N, int S)
{
    // [buf][plane][frag][512 halves]; A frag f = mh*2+kh, B frag f = nh*2+kh
    __shared__ __align__(16) _Float16 sA[2][2][4][512];
    __shared__ __align__(16) _Float16 sB[2][2][8][512];
    int tid = threadIdx.x;
    int l = tid & 63, w = tid >> 6;
    int n0 = blockIdx.x * 128, m0 = blockIdx.y * 64, s = blockIdx.z;

    int kch1 = K1 / S, kch2 = K2 / S;
    int n1 = kch1 >> 5, n2 = kch2 >> 5;
    int nit = n1 + n2;

    f32x16 accM0 = {}, accM1 = {}, accL0 = {}, accL1 = {};

    int lr = l & 31, lq = l >> 5;   // frag row-in-strip, k-quad select

    auto stage = [&](int it, int bb) {
        const _Float16 *Ah, *Al, *Wh, *Wl; int K, k0;
        if (it < n1) { Ah = Ah1; Al = Al1; Wh = Wh1; Wl = Wl1; K = K1; k0 = s * kch1 + it * 32; }
        else         { Ah = Ah2; Al = Al2; Wh = Wh2; Wl = Wl2; K = K2; k0 = s * kch2 + (it - n1) * 32; }
        #pragma unroll
        for (int qq = 0; qq < 6; ++qq) {
            int q = w * 6 + qq;              // wave-uniform frag id, 0..23
            if (q < 8) {                     // A frags: q = p*4 + mh*2 + kh
                int p = q >> 2, mh = (q >> 1) & 1, kh = q & 1;
                const _Float16* sp = p ? Al : Ah;
                int row = m0 + mh * 32 + lr;
                int gk  = k0 + kh * 16 + lq * 8;
                GLOAD_LDS16(sp + (size_t)row * K + gk, &sA[bb][p][mh * 2 + kh][0]);
            } else {                         // B frags: r = p*8 + nh*2 + kh
                int r = q - 8;
                int p = r >> 3, nh = (r >> 1) & 3, kh = r & 1;
                const _Float16* sp = p ? Wl : Wh;
                int row = n0 + nh * 32 + lr;
                int gk  = k0 + kh * 16 + lq * 8;
                GLOAD_LDS16(sp + (size_t)row * K + gk, &sB[bb][p][nh * 2 + kh][0]);
            }
        }
    };

    stage(0, 0);
    __syncthreads();                         // drains vmcnt(0) before reads

    for (int it = 0; it < nit; ++it) {
        int bb = it & 1;
        if (it + 1 < nit) stage(it + 1, bb ^ 1);
        #pragma unroll
        for (int kh = 0; kh < 2; ++kh) {
            half8 ah0 = *(const half8*)&sA[bb][0][kh][l * 8];
            half8 ah1 = *(const half8*)&sA[bb][0][2 + kh][l * 8];
            half8 al0 = *(const half8*)&sA[bb][1][kh][l * 8];
            half8 al1 = *(const half8*)&sA[bb][1][2 + kh][l * 8];
            half8 bh  = *(const half8*)&sB[bb][0][w * 2 + kh][l * 8];
            half8 bl  = *(const half8*)&sB[bb][1][w * 2 + kh][l * 8];
            accM0 = __builtin_amdgcn_mfma_f32_32x32x16_f16(ah0, bh, accM0, 0, 0, 0);
            accM1 = __builtin_amdgcn_mfma_f32_32x32x16_f16(ah1, bh, accM1, 0, 0, 0);
            accL0 = __builtin_amdgcn_mfma_f32_32x32x16_f16(ah0, bl, accL0, 0, 0, 0);
            accL1 = __builtin_amdgcn_mfma_f32_32x32x16_f16(ah1, bl, accL1, 0, 0, 0);
            accL0 = __builtin_amdgcn_mfma_f32_32x32x16_f16(al0, bh, accL0, 0, 0, 0);
            accL1 = __builtin_amdgcn_mfma_f32_32x32x16_f16(al1, bh, accL1, 0, 0, 0);
        }
        __syncthreads();                     // also drains next-stage vmcnt
    }

    // epilogue: C/D layout n = l&31, m = (r&3)+8*(r>>2)+4*(l>>5)
    float* op = outp + (size_t)s * BQ * N;
    int n = n0 + w * 32 + lr;
    float bv = bias ? bias[n] : 0.f;
    #pragma unroll
    for (int r = 0; r < 16; ++r) {
        int row = (r & 3) + 8 * (r >> 2) + 4 * lq;
        op[(size_t)(m0 + row) * N + n]      = accM0[r] + accL0[r] * (1.f / 4096.f) + bv;
        op[(size_t)(m0 + 32 + row) * N + n] = accM1[r] + accL1[r] * (1.f / 4096.f) + bv;
    }
}

// ---------------------------------------------------------------------------
// fp32 GEMM for inp = x @ w_in^T + b_in (once, K=64); writes split planes
// ---------------------------------------------------------------------------
#define GBK 16
#define GPAD 68
__global__ __launch_bounds__(256) void gemm_in(const float* __restrict__ x,
                                               const float* __restrict__ w_in,
                                               const float* __restrict__ b_in) {
    __shared__ __align__(16) float As[GBK][GPAD];
    __shared__ __align__(16) float Bs[GBK][GPAD];
    int tid = threadIdx.x;
    int tx = tid & 15, ty = tid >> 4;
    int m0 = blockIdx.y * 64, n0 = blockIdx.x * 64;
    int lm = tid >> 2, lk = (tid & 3) << 2;
    const int K = 64, N = EDIM;
    float acc[4][4] = {};
    for (int k0 = 0; k0 < K; k0 += GBK) {
        float4 av = *(const float4*)(x + (size_t)(m0 + lm) * K + k0 + lk);
        float4 wv = *(const float4*)(w_in + (size_t)(n0 + lm) * K + k0 + lk);
        As[lk + 0][lm] = av.x; As[lk + 1][lm] = av.y;
        As[lk + 2][lm] = av.z; As[lk + 3][lm] = av.w;
        Bs[lk + 0][lm] = wv.x; Bs[lk + 1][lm] = wv.y;
        Bs[lk + 2][lm] = wv.z; Bs[lk + 3][lm] = wv.w;
        __syncthreads();
        #pragma unroll
        for (int kk = 0; kk < GBK; ++kk) {
            float4 a  = *(const float4*)&As[kk][ty * 4];
            float4 bq = *(const float4*)&Bs[kk][tx * 4];
            float aa[4] = {a.x, a.y, a.z, a.w};
            float bb[4] = {bq.x, bq.y, bq.z, bq.w};
            #pragma unroll
            for (int i = 0; i < 4; ++i)
                #pragma unroll
                for (int j = 0; j < 4; ++j)
                    acc[i][j] = fmaf(aa[i], bb[j], acc[i][j]);
        }
        __syncthreads();
    }
    #pragma unroll
    for (int i = 0; i < 4; ++i) {
        int m = m0 + ty * 4 + i;
        #pragma unroll
        for (int j = 0; j < 4; ++j) {
            int n = n0 + tx * 4 + j;
            float v = acc[i][j] + b_in[n];
            split1(v, &g_curh[(size_t)m * N + n], &g_curl[(size_t)m * N + n]);
        }
    }
}

__device__ __forceinline__ float sigm(float x) { return 1.f / (1.f + expf(-x)); }

// ---------------------------------------------------------------------------
// LSTM cell 0: gates (bias included) -> h0 split planes, c0. 4 elems/thread.
// ---------------------------------------------------------------------------
__global__ void lstm0_kernel() {
    int qidx = blockIdx.x * 256 + threadIdx.x;
    int b = qidx >> 8;
    int j = (qidx & 255) * 4;
    size_t base = (size_t)b * 4096;
    float4 G[4];
    #pragma unroll
    for (int g = 0; g < 4; ++g) G[g] = *(const float4*)&g_gates[base + g * 1024 + j];
    size_t hb = (size_t)b * HDIM + j;
    float4 cin = *(const float4*)&g_c0[hb];
    float ci[4] = {cin.x, cin.y, cin.z, cin.w};
    float gi[4] = {G[0].x, G[0].y, G[0].z, G[0].w};
    float gf[4] = {G[1].x, G[1].y, G[1].z, G[1].w};
    float gg[4] = {G[2].x, G[2].y, G[2].z, G[2].w};
    float go[4] = {G[3].x, G[3].y, G[3].z, G[3].w};
    float c[4], h[4];
    half4v hh, hl;
    #pragma unroll
    for (int r = 0; r < 4; ++r) {
        c[r] = sigm(gf[r]) * ci[r] + sigm(gi[r]) * tanhf(gg[r]);
        h[r] = sigm(go[r]) * tanhf(c[r]);
        _Float16 hi16 = (_Float16)h[r];
        hh[r] = hi16;
        hl[r] = (_Float16)((h[r] - (float)hi16) * 4096.f);
    }
    *(float4*)&g_c0[hb] = {c[0], c[1], c[2], c[3]};
    *(half4v*)&g_h0h[hb] = hh;
    *(half4v*)&g_h0l[hb] = hl;
}

// ---------------------------------------------------------------------------
// LSTM cell 1 + LayerNorm: one block per row; 4 elems/thread
// ---------------------------------------------------------------------------
__global__ __launch_bounds__(256) void lstm1_ln_kernel(
    const float* __restrict__ ln_g, const float* __restrict__ ln_b)
{
    __shared__ float sbuf[4];
    int b = blockIdx.x, tid = threadIdx.x;
    int lane = tid & 63, wid = tid >> 6;
    int j = tid * 4;
    size_t base = (size_t)b * 4096;
    float4 G[4];
    #pragma unroll
    for (int g = 0; g < 4; ++g) G[g] = *(const float4*)&g_gates[base + g * 1024 + j];
    size_t hb = (size_t)b * HDIM + j;
    float4 cin = *(const float4*)&g_c1[hb];
    float ci[4] = {cin.x, cin.y, cin.z, cin.w};
    float gi[4] = {G[0].x, G[0].y, G[0].z, G[0].w};
    float gf[4] = {G[1].x, G[1].y, G[1].z, G[1].w};
    float gg[4] = {G[2].x, G[2].y, G[2].z, G[2].w};
    float go[4] = {G[3].x, G[3].y, G[3].z, G[3].w};
    float c[4], h[4];
    float sum = 0.f;
    #pragma unroll
    for (int r = 0; r < 4; ++r) {
        c[r] = sigm(gf[r]) * ci[r] + sigm(gi[r]) * tanhf(gg[r]);
        h[r] = sigm(go[r]) * tanhf(c[r]);
        sum += h[r];
    }
    *(float4*)&g_c1[hb] = {c[0], c[1], c[2], c[3]};
    half4v h1h, h1l;
    #pragma unroll
    for (int r = 0; r < 4; ++r) {
        _Float16 hi16 = (_Float16)h[r];
        h1h[r] = hi16;
        h1l[r] = (_Float16)((h[r] - (float)hi16) * 4096.f);
    }
    *(half4v*)&g_h1h[hb] = h1h;
    *(half4v*)&g_h1l[hb] = h1l;

    for (int off = 32; off > 0; off >>= 1) sum += __shfl_down(sum, off, 64);
    if (lane == 0) sbuf[wid] = sum;
    __syncthreads();
    float mu = (sbuf[0] + sbuf[1] + sbuf[2] + sbuf[3]) * (1.f / HDIM);
    __syncthreads();
    float sq = 0.f;
    #pragma unroll
    for (int r = 0; r < 4; ++r) { float d = h[r] - mu; sq += d * d; }
    for (int off = 32; off > 0; off >>= 1) sq += __shfl_down(sq, off, 64);
    if (lane == 0) sbuf[wid] = sq;
    __syncthreads();
    float var = (sbuf[0] + sbuf[1] + sbuf[2] + sbuf[3]) * (1.f / HDIM);
    float rstd = 1.f / sqrtf(var + 1e-5f);
    half4v nh, nl;
    #pragma unroll
    for (int r = 0; r < 4; ++r) {
        float hn = (h[r] - mu) * rstd * ln_g[j + r] + ln_b[j + r];
        _Float16 hi16 = (_Float16)hn;
        nh[r] = hi16;
        nl[r] = (_Float16)((hn - (float)hi16) * 4096.f);
    }
    *(half4v*)&g_hnh[hb] = nh;
    *(half4v*)&g_hnl[hb] = nl;
}

// ---------------------------------------------------------------------------
// per-row softmax over logits = sum of 4 partials + b_out
// ---------------------------------------------------------------------------
__global__ __launch_bounds__(256) void softmax_row_kernel(
    const float* __restrict__ b_out, const float* __restrict__ emb,
    float* __restrict__ out, int t)
{
    __shared__ float swv[4];
    __shared__ int   swi[4];
    __shared__ float sZ[4], sS[4];
    __shared__ float s_max;
    __shared__ int   s_idx;
    int b = blockIdx.x, tid = threadIdx.x;
    int lane = tid & 63, wid = tid >> 6;
    size_t base = (size_t)b * VDIM + 4 * tid;
    float4 xv = *(const float4*)&b_out[4 * tid];
    #pragma unroll
    for (int s = 0; s < 4; ++s) {
        float4 p = *(const float4*)&g_part_lg[(size_t)s * PLS + base];
        xv.x += p.x; xv.y += p.y; xv.z += p.z; xv.w += p.w;
    }

    float mv = xv.x; int mi = 4 * tid;
    if (xv.y > mv) { mv = xv.y; mi = 4 * tid + 1; }
    if (xv.z > mv) { mv = xv.z; mi = 4 * tid + 2; }
    if (xv.w > mv) { mv = xv.w; mi = 4 * tid + 3; }
    for (int off = 32; off > 0; off >>= 1) {
        float ov = __shfl_down(mv, off, 64);
        int   oi = __shfl_down(mi, off, 64);
        if (ov > mv || (ov == mv && oi < mi)) { mv = ov; mi = oi; }
    }
    if (lane == 0) { swv[wid] = mv; swi[wid] = mi; }
    __syncthreads();
    if (tid == 0) {
        mv = swv[0]; mi = swi[0];
        for (int w = 1; w < 4; ++w)
            if (swv[w] > mv || (swv[w] == mv && swi[w] < mi)) { mv = swv[w]; mi = swi[w]; }
        s_max = mv; s_idx = mi;
    }
    __syncthreads();
    float xmax = s_max;

    float sv[4] = {xv.x - xmax, xv.y - xmax, xv.z - xmax, xv.w - xmax};
    float z = 0.f, s1 = 0.f;
    #pragma unroll
    for (int r = 0; r < 4; ++r) { float e = expf(sv[r]); z += e; s1 += e * sv[r]; }
    for (int off = 32; off > 0; off >>= 1) {
        z  += __shfl_down(z, off, 64);
        s1 += __shfl_down(s1, off, 64);
    }
    if (lane == 0) { sZ[wid] = z; sS[wid] = s1; }
    __syncthreads();
    if (tid == 0) {
        float Z = sZ[0] + sZ[1] + sZ[2] + sZ[3];
        float S1 = sS[0] + sS[1] + sS[2] + sS[3];
        float logZ = logf(Z);
        float ent = logZ - S1 / Z;
        out[(size_t)b * TOUT + t]                         = (float)s_idx;
        out[(size_t)BQ * TOUT + (size_t)b * TOUT + t]     = -logZ;
        out[(size_t)2 * BQ * TOUT + (size_t)b * TOUT + t] = ent;
    }
    __syncthreads();
    int sym = s_idx;
    const float* e = emb + (size_t)sym * EDIM;
    for (int j = tid; j < EDIM; j += 256)
        split1(e[j], &g_curh[(size_t)b * EDIM + j], &g_curl[(size_t)b * EDIM + j]);
}

// ---------------------------------------------------------------------------
extern "C" void kernel_launch(void* const* d_in, const int* in_sizes, int n_in,
                              void* d_out, int out_size, void* d_ws, size_t ws_size,
                              hipStream_t stream) {
    const float* x     = (const float*)d_in[0];
    const float* w_in  = (const float*)d_in[1];
    const float* b_in  = (const float*)d_in[2];
    const float* w_ih0 = (const float*)d_in[3];
    const float* w_hh0 = (const float*)d_in[4];
    const float* b_ih0 = (const float*)d_in[5];
    const float* b_hh0 = (const float*)d_in[6];
    const float* w_ih1 = (const float*)d_in[7];
    const float* w_hh1 = (const float*)d_in[8];
    const float* b_ih1 = (const float*)d_in[9];
    const float* b_hh1 = (const float*)d_in[10];
    const float* ln_g  = (const float*)d_in[11];
    const float* ln_b  = (const float*)d_in[12];
    const float* w_out = (const float*)d_in[13];
    const float* b_out = (const float*)d_in[14];
    const float* emb   = (const float*)d_in[15];
    float* out = (float*)d_out;

    _Float16 *wih0h, *wih0l, *whh0h, *whh0l, *wih1h, *wih1l, *whh1h, *whh1l, *wouth, *woutl;
    hipGetSymbolAddress((void**)&wih0h, HIP_SYMBOL(g_wih0h));
    hipGetSymbolAddress((void**)&wih0l, HIP_SYMBOL(g_wih0l));
    hipGetSymbolAddress((void**)&whh0h, HIP_SYMBOL(g_whh0h));
    hipGetSymbolAddress((void**)&whh0l, HIP_SYMBOL(g_whh0l));
    hipGetSymbolAddress((void**)&wih1h, HIP_SYMBOL(g_wih1h));
    hipGetSymbolAddress((void**)&wih1l, HIP_SYMBOL(g_wih1l));
    hipGetSymbolAddress((void**)&whh1h, HIP_SYMBOL(g_whh1h));
    hipGetSymbolAddress((void**)&whh1l, HIP_SYMBOL(g_whh1l));
    hipGetSymbolAddress((void**)&wouth, HIP_SYMBOL(g_wouth));
    hipGetSymbolAddress((void**)&woutl, HIP_SYMBOL(g_woutl));
    _Float16 *curh, *curl, *h0h, *h0l, *h1h, *h1l, *hnh, *hnl;
    hipGetSymbolAddress((void**)&curh, HIP_SYMBOL(g_curh));
    hipGetSymbolAddress((void**)&curl, HIP_SYMBOL(g_curl));
    hipGetSymbolAddress((void**)&h0h, HIP_SYMBOL(g_h0h));
    hipGetSymbolAddress((void**)&h0l, HIP_SYMBOL(g_h0l));
    hipGetSymbolAddress((void**)&h1h, HIP_SYMBOL(g_h1h));
    hipGetSymbolAddress((void**)&h1l, HIP_SYMBOL(g_h1l));
    hipGetSymbolAddress((void**)&hnh, HIP_SYMBOL(g_hnh));
    hipGetSymbolAddress((void**)&hnl, HIP_SYMBOL(g_hnl));
    float *gates, *part_lg, *bsum0, *bsum1;
    hipGetSymbolAddress((void**)&gates, HIP_SYMBOL(g_gates));
    hipGetSymbolAddress((void**)&part_lg, HIP_SYMBOL(g_part_lg));
    hipGetSymbolAddress((void**)&bsum0, HIP_SYMBOL(g_bsum0));
    hipGetSymbolAddress((void**)&bsum1, HIP_SYMBOL(g_bsum1));

    init_kernel<<<(BQ * HDIM) / 256, 256, 0, stream>>>(out, b_ih0, b_hh0, b_ih1, b_hh1);

    split_kernel<<<(4*HDIM*EDIM/4 + 255)/256, 256, 0, stream>>>(w_ih0, wih0h, wih0l, 4*HDIM*EDIM/4);
    split_kernel<<<(4*HDIM*HDIM/4 + 255)/256, 256, 0, stream>>>(w_hh0, whh0h, whh0l, 4*HDIM*HDIM/4);
    split_kernel<<<(4*HDIM*HDIM/4 + 255)/256, 256, 0, stream>>>(w_ih1, wih1h, wih1l, 4*HDIM*HDIM/4);
    split_kernel<<<(4*HDIM*HDIM/4 + 255)/256, 256, 0, stream>>>(w_hh1, whh1h, whh1l, 4*HDIM*HDIM/4);
    split_kernel<<<(VDIM*HDIM/4 + 255)/256, 256, 0, stream>>>(w_out, wouth, woutl, VDIM*HDIM/4);

    gemm_in<<<dim3(EDIM / 64, BQ / 64), 256, 0, stream>>>(x, w_in, b_in);

    for (int t = 0; t < TLEN; ++t) {
        // gates0 = cur @ w_ih0^T + h0 @ w_hh0^T + bsum0   (S=1, direct)
        gemm_f16split<<<dim3(4 * HDIM / 128, BQ / 64, 1), 256, 0, stream>>>(
            curh, curl, EDIM, wih0h, wih0l,
            h0h, h0l, HDIM, whh0h, whh0l,
            bsum0, gates, 4 * HDIM, 1);
        lstm0_kernel<<<(BQ * HDIM / 4) / 256, 256, 0, stream>>>();

        // gates1 = h0 @ w_ih1^T + h1 @ w_hh1^T + bsum1   (S=1, direct)
        gemm_f16split<<<dim3(4 * HDIM / 128, BQ / 64, 1), 256, 0, stream>>>(
            h0h, h0l, HDIM, wih1h, wih1l,
            h1h, h1l, HDIM, whh1h, whh1l,
            bsum1, gates, 4 * HDIM, 1);
        lstm1_ln_kernel<<<BQ, 256, 0, stream>>>(ln_g, ln_b);

        // logits partials = hn @ w_out^T   (S=4)
        gemm_f16split<<<dim3(VDIM / 128, BQ / 64, 4), 256, 0, stream>>>(
            hnh, hnl, HDIM, wouth, woutl,
            (const _Float16*)nullptr, (const _Float16*)nullptr, 0,
            (const _Float16*)nullptr, (const _Float16*)nullptr,
            (const float*)nullptr, part_lg, VDIM, 4);

        softmax_row_kernel<<<BQ, 256, 0, stream>>>(b_out, emb, out, t);
    }
}

// Round 6
// 2942.724 us; speedup vs baseline: 2.0256x; 2.0256x over previous
//
#include <hip/hip_runtime.h>
#include <hip/hip_bf16.h>
#include <math.h>

#define BQ   512
#define EDIM 512
#define HDIM 1024
#define VDIM 1024
#define TLEN 32
#define TOUT 33
#define PGS  (BQ * 4 * HDIM)   // gate partial plane stride
#define PLS  (BQ * VDIM)       // logits partial plane stride

typedef _Float16 half8  __attribute__((ext_vector_type(8)));
typedef _Float16 half4v __attribute__((ext_vector_type(4)));
typedef float    f32x16 __attribute__((ext_vector_type(16)));

#define GLOAD_LDS16(gp, lp) __builtin_amdgcn_global_load_lds( \
    (const __attribute__((address_space(1))) void*)(gp),      \
    (__attribute__((address_space(3))) void*)(lp), 16, 0, 0)

// Packed fragment layout for an [R][K] f16 plane (K = 512 or 1024, pow2):
// element (r,k) -> (r>>5)*(32K) + (k>>4)*512 + ((k>>3)&1)*256 + (r&31)*8 + (k&7)
// => each (32-row strip, 16-k block) is a contiguous 1KB block where lane l
//    owns halves [l*8, l*8+8) = row (l&31), k-half (l>>5). Matches MFMA frag.
__device__ __forceinline__ size_t packoff(int r, int k, int K) {
    return (size_t)(r >> 5) * (size_t)(32 * K) + (size_t)(k >> 4) * 512
         + (size_t)((k >> 3) & 1) * 256 + (size_t)(r & 31) * 8 + (size_t)(k & 7);
}

// ---------------------------------------------------------------------------
// Static device buffers — write-before-read each call.
// value = hi + lo/4096 (lo pre-scaled by 2^12)
// ---------------------------------------------------------------------------
__device__ _Float16 g_curh[BQ*EDIM], g_curl[BQ*EDIM];       // packed K=512
__device__ _Float16 g_h0h[BQ*HDIM], g_h0l[BQ*HDIM];         // packed K=1024
__device__ _Float16 g_h1h[BQ*HDIM], g_h1l[BQ*HDIM];         // packed K=1024
__device__ _Float16 g_hnh[BQ*HDIM], g_hnl[BQ*HDIM];         // packed K=1024
__device__ float    g_c0[BQ*HDIM], g_c1[BQ*HDIM];

__device__ _Float16 g_wih0h[4*HDIM*EDIM], g_wih0l[4*HDIM*EDIM];  // packed K=512
__device__ _Float16 g_whh0h[4*HDIM*HDIM], g_whh0l[4*HDIM*HDIM];  // packed K=1024
__device__ _Float16 g_wih1h[4*HDIM*HDIM], g_wih1l[4*HDIM*HDIM];  // packed K=1024
__device__ _Float16 g_whh1h[4*HDIM*HDIM], g_whh1l[4*HDIM*HDIM];  // packed K=1024
__device__ _Float16 g_wouth[VDIM*HDIM],   g_woutl[VDIM*HDIM];    // packed K=1024

__device__ float g_part_g[2 * PGS];    // gate GEMM split-K partials (S=2)
__device__ float g_part_lg[8 * PLS];   // logits split-K partials (S=8)
__device__ float g_bsum0[4*HDIM], g_bsum1[4*HDIM];

// ---------------------------------------------------------------------------
__global__ void init_kernel(float* __restrict__ out,
                            const float* __restrict__ bi0, const float* __restrict__ bh0,
                            const float* __restrict__ bi1, const float* __restrict__ bh1) {
    int i = blockIdx.x * 256 + threadIdx.x;   // [0, BQ*HDIM)
    g_c0[i] = 0.f; g_c1[i] = 0.f;
    g_h0h[i] = (_Float16)0.f; g_h0l[i] = (_Float16)0.f;
    g_h1h[i] = (_Float16)0.f; g_h1l[i] = (_Float16)0.f;
    if (i < 4 * HDIM) {
        g_bsum0[i] = bi0[i] + bh0[i];
        g_bsum1[i] = bi1[i] + bh1[i];
    }
    if (i < 3 * BQ) {
        int which = i / BQ, b = i % BQ;
        out[(size_t)which * BQ * TOUT + (size_t)b * TOUT + (TOUT - 1)] = 0.f;
    }
}

// ---------------------------------------------------------------------------
// fp32 [R][K] -> packed (hi, lo*2^12) f16 planes. klog = log2(K).
// ---------------------------------------------------------------------------
__global__ void split_pack_kernel(const float* __restrict__ w, _Float16* __restrict__ hi,
                                  _Float16* __restrict__ lo, int klog, int nquads) {
    int q = blockIdx.x * 256 + threadIdx.x;
    if (q >= nquads) return;
    int e = q * 4;
    int r = e >> klog, k = e & ((1 << klog) - 1);
    float4 v = ((const float4*)w)[q];
    half4v h, l;
    h[0] = (_Float16)v.x; l[0] = (_Float16)((v.x - (float)h[0]) * 4096.f);
    h[1] = (_Float16)v.y; l[1] = (_Float16)((v.y - (float)h[1]) * 4096.f);
    h[2] = (_Float16)v.z; l[2] = (_Float16)((v.z - (float)h[2]) * 4096.f);
    h[3] = (_Float16)v.w; l[3] = (_Float16)((v.w - (float)h[3]) * 4096.f);
    size_t po = packoff(r, k, 1 << klog);     // k%4==0 -> 4 contiguous halves
    *(half4v*)&hi[po] = h;
    *(half4v*)&lo[po] = l;
}

__device__ __forceinline__ void split1(float x, _Float16* hp, _Float16* lp) {
    _Float16 h = (_Float16)x;
    *hp = h;
    *lp = (_Float16)((x - (float)h) * 4096.f);
}

// ---------------------------------------------------------------------------
// MFMA GEMM, tile 64(M)x128(N), 4 waves; wave w owns n-strip w*32. BK=32.
// A (hi+lo) staged to LDS via global_load_lds from PACKED layout (coalesced,
// conflict-free, 16KB dbuf). B (hi+lo) loaded global->VGPR per wave from
// PACKED layout, register-double-buffered (no LDS for B: zero cross-wave
// reuse). Split-K over blockIdx.z: out plane s. nit must be even.
// ---------------------------------------------------------------------------
__global__ __launch_bounds__(256, 2) void gemm_f16split(
    const _Float16* __restrict__ Ah1, const _Float16* __restrict__ Al1, int K1,
    const _Float16* __restrict__ Wh1, const _Float16* __restrict__ Wl1,
    const _Float16* __restrict__ Ah2, const _Float16* __restrict__ Al2, int K2,
    const _Float16* __restrict__ Wh2, const _Float16* __restrict__ Wl2,
    float* __restrict__ outp, int N, int S)
{
    __shared__ __align__(16) _Float16 sA[2][2][2][2][512]; // [buf][pl][mh][kh]
    int tid = threadIdx.x;
    int l = tid & 63, w = tid >> 6;
    int n0 = blockIdx.x * 128, m0 = blockIdx.y * 64, s = blockIdx.z;

    int kch1 = K1 / S, kch2 = K2 / S;
    int n1 = kch1 >> 5, n2 = kch2 >> 5;
    int nit = n1 + n2;

    f32x16 accM0 = {}, accM1 = {}, accL0 = {}, accL1 = {};
    int lr = l & 31, lq = l >> 5;

    auto stageA = [&](int it, int bb) {
        const _Float16 *AhP, *AlP; int K, k0;
        if (it < n1) { AhP = Ah1; AlP = Al1; K = K1; k0 = s * kch1 + it * 32; }
        else         { AhP = Ah2; AlP = Al2; K = K2; k0 = s * kch2 + (it - n1) * 32; }
        #pragma unroll
        for (int qq = 0; qq < 2; ++qq) {
            int q = w * 2 + qq;                  // 8 frags, 2 per wave
            int pl = q >> 2, mh = (q >> 1) & 1, kh = q & 1;
            const _Float16* sp = pl ? AlP : AhP;
            size_t off = (size_t)((m0 >> 5) + mh) * (size_t)(32 * K)
                       + (size_t)((k0 >> 4) + kh) * 512 + (size_t)l * 8;
            GLOAD_LDS16(sp + off, &sA[bb][pl][mh][kh][0]);
        }
    };

    auto loadB = [&](int it, half8 (&Bh)[2], half8 (&Bl)[2]) {
        const _Float16 *WhP, *WlP; int K, k0;
        if (it < n1) { WhP = Wh1; WlP = Wl1; K = K1; k0 = s * kch1 + it * 32; }
        else         { WhP = Wh2; WlP = Wl2; K = K2; k0 = s * kch2 + (it - n1) * 32; }
        size_t strip = (size_t)((n0 >> 5) + w) * (size_t)(32 * K);
        #pragma unroll
        for (int kh = 0; kh < 2; ++kh) {
            size_t off = strip + (size_t)((k0 >> 4) + kh) * 512 + (size_t)l * 8;
            Bh[kh] = *(const half8*)(WhP + off);
            Bl[kh] = *(const half8*)(WlP + off);
        }
    };

    auto compute = [&](int bb, half8 (&Bh)[2], half8 (&Bl)[2]) {
        #pragma unroll
        for (int kh = 0; kh < 2; ++kh) {
            half8 ah0 = *(const half8*)&sA[bb][0][0][kh][(size_t)l * 8];
            half8 ah1 = *(const half8*)&sA[bb][0][1][kh][(size_t)l * 8];
            half8 al0 = *(const half8*)&sA[bb][1][0][kh][(size_t)l * 8];
            half8 al1 = *(const half8*)&sA[bb][1][1][kh][(size_t)l * 8];
            accM0 = __builtin_amdgcn_mfma_f32_32x32x16_f16(ah0, Bh[kh], accM0, 0, 0, 0);
            accM1 = __builtin_amdgcn_mfma_f32_32x32x16_f16(ah1, Bh[kh], accM1, 0, 0, 0);
            accL0 = __builtin_amdgcn_mfma_f32_32x32x16_f16(ah0, Bl[kh], accL0, 0, 0, 0);
            accL1 = __builtin_amdgcn_mfma_f32_32x32x16_f16(ah1, Bl[kh], accL1, 0, 0, 0);
            accL0 = __builtin_amdgcn_mfma_f32_32x32x16_f16(al0, Bh[kh], accL0, 0, 0, 0);
            accL1 = __builtin_amdgcn_mfma_f32_32x32x16_f16(al1, Bh[kh], accL1, 0, 0, 0);
        }
    };

    half8 B0h[2], B0l[2], B1h[2], B1l[2];
    stageA(0, 0);
    loadB(0, B0h, B0l);
    __syncthreads();

    for (int itp = 0; itp < nit; itp += 2) {
        if (itp + 1 < nit) { stageA(itp + 1, 1); loadB(itp + 1, B1h, B1l); }
        compute(0, B0h, B0l);
        __syncthreads();
        if (itp + 2 < nit) { stageA(itp + 2, 0); loadB(itp + 2, B0h, B0l); }
        compute(1, B1h, B1l);
        __syncthreads();
    }

    // epilogue: C/D layout n = l&31, m = (r&3)+8*(r>>2)+4*(l>>5)
    float* op = outp + (size_t)s * BQ * N;
    int n = n0 + w * 32 + lr;
    #pragma unroll
    for (int r = 0; r < 16; ++r) {
        int row = (r & 3) + 8 * (r >> 2) + 4 * lq;
        op[(size_t)(m0 + row) * N + n]      = accM0[r] + accL0[r] * (1.f / 4096.f);
        op[(size_t)(m0 + 32 + row) * N + n] = accM1[r] + accL1[r] * (1.f / 4096.f);
    }
}

// ---------------------------------------------------------------------------
// fp32 GEMM for inp = x @ w_in^T + b_in (once, K=64); writes packed cur
// ---------------------------------------------------------------------------
#define GBK 16
#define GPAD 68
__global__ __launch_bounds__(256) void gemm_in(const float* __restrict__ x,
                                               const float* __restrict__ w_in,
                                               const float* __restrict__ b_in) {
    __shared__ __align__(16) float As[GBK][GPAD];
    __shared__ __align__(16) float Bs[GBK][GPAD];
    int tid = threadIdx.x;
    int tx = tid & 15, ty = tid >> 4;
    int m0 = blockIdx.y * 64, n0 = blockIdx.x * 64;
    int lm = tid >> 2, lk = (tid & 3) << 2;
    const int K = 64;
    float acc[4][4] = {};
    for (int k0 = 0; k0 < K; k0 += GBK) {
        float4 av = *(const float4*)(x + (size_t)(m0 + lm) * K + k0 + lk);
        float4 wv = *(const float4*)(w_in + (size_t)(n0 + lm) * K + k0 + lk);
        As[lk + 0][lm] = av.x; As[lk + 1][lm] = av.y;
        As[lk + 2][lm] = av.z; As[lk + 3][lm] = av.w;
        Bs[lk + 0][lm] = wv.x; Bs[lk + 1][lm] = wv.y;
        Bs[lk + 2][lm] = wv.z; Bs[lk + 3][lm] = wv.w;
        __syncthreads();
        #pragma unroll
        for (int kk = 0; kk < GBK; ++kk) {
            float4 a  = *(const float4*)&As[kk][ty * 4];
            float4 bq = *(const float4*)&Bs[kk][tx * 4];
            float aa[4] = {a.x, a.y, a.z, a.w};
            float bb[4] = {bq.x, bq.y, bq.z, bq.w};
            #pragma unroll
            for (int i = 0; i < 4; ++i)
                #pragma unroll
                for (int j = 0; j < 4; ++j)
                    acc[i][j] = fmaf(aa[i], bb[j], acc[i][j]);
        }
        __syncthreads();
    }
    #pragma unroll
    for (int i = 0; i < 4; ++i) {
        int m = m0 + ty * 4 + i;
        int n = n0 + tx * 4;
        half4v h, lo;
        #pragma unroll
        for (int j = 0; j < 4; ++j) {
            float v = acc[i][j] + b_in[n + j];
            _Float16 hv = (_Float16)v;
            h[j] = hv;
            lo[j] = (_Float16)((v - (float)hv) * 4096.f);
        }
        size_t po = packoff(m, n, EDIM);
        *(half4v*)&g_curh[po] = h;
        *(half4v*)&g_curl[po] = lo;
    }
}

__device__ __forceinline__ float sigm(float x) { return 1.f / (1.f + expf(-x)); }

// ---------------------------------------------------------------------------
// LSTM cell 0: gates = part0+part1+bsum0 -> h0 (packed K=1024), c0.
// ---------------------------------------------------------------------------
__global__ void lstm0_kernel() {
    int qidx = blockIdx.x * 256 + threadIdx.x;
    int b = qidx >> 8;
    int j = (qidx & 255) * 4;
    size_t base = (size_t)b * 4096;
    float4 G[4];
    #pragma unroll
    for (int g = 0; g < 4; ++g) {
        float4 p0 = *(const float4*)&g_part_g[base + g * 1024 + j];
        float4 p1 = *(const float4*)&g_part_g[PGS + base + g * 1024 + j];
        float4 bs = *(const float4*)&g_bsum0[g * 1024 + j];
        G[g].x = p0.x + p1.x + bs.x;
        G[g].y = p0.y + p1.y + bs.y;
        G[g].z = p0.z + p1.z + bs.z;
        G[g].w = p0.w + p1.w + bs.w;
    }
    size_t hb = (size_t)b * HDIM + j;
    float4 cin = *(const float4*)&g_c0[hb];
    float ci[4] = {cin.x, cin.y, cin.z, cin.w};
    float gi[4] = {G[0].x, G[0].y, G[0].z, G[0].w};
    float gf[4] = {G[1].x, G[1].y, G[1].z, G[1].w};
    float gg[4] = {G[2].x, G[2].y, G[2].z, G[2].w};
    float go[4] = {G[3].x, G[3].y, G[3].z, G[3].w};
    float c[4], h[4];
    half4v hh, hl;
    #pragma unroll
    for (int r = 0; r < 4; ++r) {
        c[r] = sigm(gf[r]) * ci[r] + sigm(gi[r]) * tanhf(gg[r]);
        h[r] = sigm(go[r]) * tanhf(c[r]);
        _Float16 hi16 = (_Float16)h[r];
        hh[r] = hi16;
        hl[r] = (_Float16)((h[r] - (float)hi16) * 4096.f);
    }
    *(float4*)&g_c0[hb] = {c[0], c[1], c[2], c[3]};
    size_t po = packoff(b, j, HDIM);
    *(half4v*)&g_h0h[po] = hh;
    *(half4v*)&g_h0l[po] = hl;
}

// ---------------------------------------------------------------------------
// LSTM cell 1 + LayerNorm: one block per row; writes packed h1, hn.
// ---------------------------------------------------------------------------
__global__ __launch_bounds__(256) void lstm1_ln_kernel(
    const float* __restrict__ ln_g, const float* __restrict__ ln_b)
{
    __shared__ float sbuf[4];
    int b = blockIdx.x, tid = threadIdx.x;
    int lane = tid & 63, wid = tid >> 6;
    int j = tid * 4;
    size_t base = (size_t)b * 4096;
    float4 G[4];
    #pragma unroll
    for (int g = 0; g < 4; ++g) {
        float4 p0 = *(const float4*)&g_part_g[base + g * 1024 + j];
        float4 p1 = *(const float4*)&g_part_g[PGS + base + g * 1024 + j];
        float4 bs = *(const float4*)&g_bsum1[g * 1024 + j];
        G[g].x = p0.x + p1.x + bs.x;
        G[g].y = p0.y + p1.y + bs.y;
        G[g].z = p0.z + p1.z + bs.z;
        G[g].w = p0.w + p1.w + bs.w;
    }
    size_t hb = (size_t)b * HDIM + j;
    float4 cin = *(const float4*)&g_c1[hb];
    float ci[4] = {cin.x, cin.y, cin.z, cin.w};
    float gi[4] = {G[0].x, G[0].y, G[0].z, G[0].w};
    float gf[4] = {G[1].x, G[1].y, G[1].z, G[1].w};
    float gg[4] = {G[2].x, G[2].y, G[2].z, G[2].w};
    float go[4] = {G[3].x, G[3].y, G[3].z, G[3].w};
    float c[4], h[4];
    float sum = 0.f;
    #pragma unroll
    for (int r = 0; r < 4; ++r) {
        c[r] = sigm(gf[r]) * ci[r] + sigm(gi[r]) * tanhf(gg[r]);
        h[r] = sigm(go[r]) * tanhf(c[r]);
        sum += h[r];
    }
    *(float4*)&g_c1[hb] = {c[0], c[1], c[2], c[3]};
    size_t po = packoff(b, j, HDIM);
    half4v h1h, h1l;
    #pragma unroll
    for (int r = 0; r < 4; ++r) {
        _Float16 hi16 = (_Float16)h[r];
        h1h[r] = hi16;
        h1l[r] = (_Float16)((h[r] - (float)hi16) * 4096.f);
    }
    *(half4v*)&g_h1h[po] = h1h;
    *(half4v*)&g_h1l[po] = h1l;

    for (int off = 32; off > 0; off >>= 1) sum += __shfl_down(sum, off, 64);
    if (lane == 0) sbuf[wid] = sum;
    __syncthreads();
    float mu = (sbuf[0] + sbuf[1] + sbuf[2] + sbuf[3]) * (1.f / HDIM);
    __syncthreads();
    float sq = 0.f;
    #pragma unroll
    for (int r = 0; r < 4; ++r) { float d = h[r] - mu; sq += d * d; }
    for (int off = 32; off > 0; off >>= 1) sq += __shfl_down(sq, off, 64);
    if (lane == 0) sbuf[wid] = sq;
    __syncthreads();
    float var = (sbuf[0] + sbuf[1] + sbuf[2] + sbuf[3]) * (1.f / HDIM);
    float rstd = 1.f / sqrtf(var + 1e-5f);
    half4v nh, nl;
    #pragma unroll
    for (int r = 0; r < 4; ++r) {
        float hn = (h[r] - mu) * rstd * ln_g[j + r] + ln_b[j + r];
        _Float16 hi16 = (_Float16)hn;
        nh[r] = hi16;
        nl[r] = (_Float16)((hn - (float)hi16) * 4096.f);
    }
    *(half4v*)&g_hnh[po] = nh;
    *(half4v*)&g_hnl[po] = nl;
}

// ---------------------------------------------------------------------------
// per-row softmax over logits = sum of 8 partials + b_out; writes packed cur
// ---------------------------------------------------------------------------
__global__ __launch_bounds__(256) void softmax_row_kernel(
    const float* __restrict__ b_out, const float* __restrict__ emb,
    float* __restrict__ out, int t)
{
    __shared__ float swv[4];
    __shared__ int   swi[4];
    __shared__ float sZ[4], sS[4];
    __shared__ float s_max;
    __shared__ int   s_idx;
    int b = blockIdx.x, tid = threadIdx.x;
    int lane = tid & 63, wid = tid >> 6;
    size_t base = (size_t)b * VDIM + 4 * tid;
    float4 xv = *(const float4*)&b_out[4 * tid];
    #pragma unroll
    for (int s = 0; s < 8; ++s) {
        float4 p = *(const float4*)&g_part_lg[(size_t)s * PLS + base];
        xv.x += p.x; xv.y += p.y; xv.z += p.z; xv.w += p.w;
    }

    float mv = xv.x; int mi = 4 * tid;
    if (xv.y > mv) { mv = xv.y; mi = 4 * tid + 1; }
    if (xv.z > mv) { mv = xv.z; mi = 4 * tid + 2; }
    if (xv.w > mv) { mv = xv.w; mi = 4 * tid + 3; }
    for (int off = 32; off > 0; off >>= 1) {
        float ov = __shfl_down(mv, off, 64);
        int   oi = __shfl_down(mi, off, 64);
        if (ov > mv || (ov == mv && oi < mi)) { mv = ov; mi = oi; }
    }
    if (lane == 0) { swv[wid] = mv; swi[wid] = mi; }
    __syncthreads();
    if (tid == 0) {
        mv = swv[0]; mi = swi[0];
        for (int w = 1; w < 4; ++w)
            if (swv[w] > mv || (swv[w] == mv && swi[w] < mi)) { mv = swv[w]; mi = swi[w]; }
        s_max = mv; s_idx = mi;
    }
    __syncthreads();
    float xmax = s_max;

    float sv[4] = {xv.x - xmax, xv.y - xmax, xv.z - xmax, xv.w - xmax};
    float z = 0.f, s1 = 0.f;
    #pragma unroll
    for (int r = 0; r < 4; ++r) { float e = expf(sv[r]); z += e; s1 += e * sv[r]; }
    for (int off = 32; off > 0; off >>= 1) {
        z  += __shfl_down(z, off, 64);
        s1 += __shfl_down(s1, off, 64);
    }
    if (lane == 0) { sZ[wid] = z; sS[wid] = s1; }
    __syncthreads();
    if (tid == 0) {
        float Z = sZ[0] + sZ[1] + sZ[2] + sZ[3];
        float S1 = sS[0] + sS[1] + sS[2] + sS[3];
        float logZ = logf(Z);
        float ent = logZ - S1 / Z;
        out[(size_t)b * TOUT + t]                         = (float)s_idx;
        out[(size_t)BQ * TOUT + (size_t)b * TOUT + t]     = -logZ;
        out[(size_t)2 * BQ * TOUT + (size_t)b * TOUT + t] = ent;
    }
    __syncthreads();
    int sym = s_idx;
    const float* e = emb + (size_t)sym * EDIM;
    for (int j = tid; j < EDIM; j += 256) {
        size_t po = packoff(b, j, EDIM);
        split1(e[j], &g_curh[po], &g_curl[po]);
    }
}

// ---------------------------------------------------------------------------
extern "C" void kernel_launch(void* const* d_in, const int* in_sizes, int n_in,
                              void* d_out, int out_size, void* d_ws, size_t ws_size,
                              hipStream_t stream) {
    const float* x     = (const float*)d_in[0];
    const float* w_in  = (const float*)d_in[1];
    const float* b_in  = (const float*)d_in[2];
    const float* w_ih0 = (const float*)d_in[3];
    const float* w_hh0 = (const float*)d_in[4];
    const float* b_ih0 = (const float*)d_in[5];
    const float* b_hh0 = (const float*)d_in[6];
    const float* w_ih1 = (const float*)d_in[7];
    const float* w_hh1 = (const float*)d_in[8];
    const float* b_ih1 = (const float*)d_in[9];
    const float* b_hh1 = (const float*)d_in[10];
    const float* ln_g  = (const float*)d_in[11];
    const float* ln_b  = (const float*)d_in[12];
    const float* w_out = (const float*)d_in[13];
    const float* b_out = (const float*)d_in[14];
    const float* emb   = (const float*)d_in[15];
    float* out = (float*)d_out;

    _Float16 *wih0h, *wih0l, *whh0h, *whh0l, *wih1h, *wih1l, *whh1h, *whh1l, *wouth, *woutl;
    hipGetSymbolAddress((void**)&wih0h, HIP_SYMBOL(g_wih0h));
    hipGetSymbolAddress((void**)&wih0l, HIP_SYMBOL(g_wih0l));
    hipGetSymbolAddress((void**)&whh0h, HIP_SYMBOL(g_whh0h));
    hipGetSymbolAddress((void**)&whh0l, HIP_SYMBOL(g_whh0l));
    hipGetSymbolAddress((void**)&wih1h, HIP_SYMBOL(g_wih1h));
    hipGetSymbolAddress((void**)&wih1l, HIP_SYMBOL(g_wih1l));
    hipGetSymbolAddress((void**)&whh1h, HIP_SYMBOL(g_whh1h));
    hipGetSymbolAddress((void**)&whh1l, HIP_SYMBOL(g_whh1l));
    hipGetSymbolAddress((void**)&wouth, HIP_SYMBOL(g_wouth));
    hipGetSymbolAddress((void**)&woutl, HIP_SYMBOL(g_woutl));
    _Float16 *curh, *curl, *h0h, *h0l, *h1h, *h1l, *hnh, *hnl;
    hipGetSymbolAddress((void**)&curh, HIP_SYMBOL(g_curh));
    hipGetSymbolAddress((void**)&curl, HIP_SYMBOL(g_curl));
    hipGetSymbolAddress((void**)&h0h, HIP_SYMBOL(g_h0h));
    hipGetSymbolAddress((void**)&h0l, HIP_SYMBOL(g_h0l));
    hipGetSymbolAddress((void**)&h1h, HIP_SYMBOL(g_h1h));
    hipGetSymbolAddress((void**)&h1l, HIP_SYMBOL(g_h1l));
    hipGetSymbolAddress((void**)&hnh, HIP_SYMBOL(g_hnh));
    hipGetSymbolAddress((void**)&hnl, HIP_SYMBOL(g_hnl));
    float *part_g, *part_lg;
    hipGetSymbolAddress((void**)&part_g, HIP_SYMBOL(g_part_g));
    hipGetSymbolAddress((void**)&part_lg, HIP_SYMBOL(g_part_lg));

    init_kernel<<<(BQ * HDIM) / 256, 256, 0, stream>>>(out, b_ih0, b_hh0, b_ih1, b_hh1);

    // one-time weight split+pack (klog = log2 K)
    split_pack_kernel<<<(4*HDIM*EDIM/4 + 255)/256, 256, 0, stream>>>(w_ih0, wih0h, wih0l, 9,  4*HDIM*EDIM/4);
    split_pack_kernel<<<(4*HDIM*HDIM/4 + 255)/256, 256, 0, stream>>>(w_hh0, whh0h, whh0l, 10, 4*HDIM*HDIM/4);
    split_pack_kernel<<<(4*HDIM*HDIM/4 + 255)/256, 256, 0, stream>>>(w_ih1, wih1h, wih1l, 10, 4*HDIM*HDIM/4);
    split_pack_kernel<<<(4*HDIM*HDIM/4 + 255)/256, 256, 0, stream>>>(w_hh1, whh1h, whh1l, 10, 4*HDIM*HDIM/4);
    split_pack_kernel<<<(VDIM*HDIM/4 + 255)/256, 256, 0, stream>>>(w_out, wouth, woutl, 10, VDIM*HDIM/4);

    gemm_in<<<dim3(EDIM / 64, BQ / 64), 256, 0, stream>>>(x, w_in, b_in);

    for (int t = 0; t < TLEN; ++t) {
        // gates0 = cur @ w_ih0^T + h0 @ w_hh0^T   (S=2 -> part_g planes)
        gemm_f16split<<<dim3(4 * HDIM / 128, BQ / 64, 2), 256, 0, stream>>>(
            curh, curl, EDIM, wih0h, wih0l,
            h0h, h0l, HDIM, whh0h, whh0l,
            part_g, 4 * HDIM, 2);
        lstm0_kernel<<<(BQ * HDIM / 4) / 256, 256, 0, stream>>>();

        // gates1 = h0 @ w_ih1^T + h1 @ w_hh1^T   (S=2 -> part_g planes)
        gemm_f16split<<<dim3(4 * HDIM / 128, BQ / 64, 2), 256, 0, stream>>>(
            h0h, h0l, HDIM, wih1h, wih1l,
            h1h, h1l, HDIM, whh1h, whh1l,
            part_g, 4 * HDIM, 2);
        lstm1_ln_kernel<<<BQ, 256, 0, stream>>>(ln_g, ln_b);

        // logits partials = hn @ w_out^T   (S=8 -> part_lg planes)
        gemm_f16split<<<dim3(VDIM / 128, BQ / 64, 8), 256, 0, stream>>>(
            hnh, hnl, HDIM, wouth, woutl,
            (const _Float16*)nullptr, (const _Float16*)nullptr, 0,
            (const _Float16*)nullptr, (const _Float16*)nullptr,
            part_lg, VDIM, 8);

        softmax_row_kernel<<<BQ, 256, 0, stream>>>(b_out, emb, out, t);
    }
}